// Round 5
// baseline (25438.881 us; speedup 1.0000x reference)
//
#include <hip/hip_runtime.h>
#include <hip/hip_fp16.h>
#include <math.h>

#define TSTEPS 16384
#define NTAGS  1024
#define NWG    128
#define TPB    64
#define ROWS   8
#define START_I 1022
#define STOP_I  1023
#define EPS     6.103515625e-05f   // 2^-14, smallest normal fp16
#define FLOOR_F 6.2e-05f           // producer clamp (rounds to >= EPS in fp16)
#define CEIL_F  60000.0f           // overflow guard (fp16 max 65504)
#define SCALE_C 0.0625f            // 2^-4 headroom scale, transparent to algebra
#define LOG2_C  4.0                // -log2(SCALE_C)

// CRF forward, linear (exp) domain. fp16 ring (NO offset -> no quantization
// floor at 1.0; round-3 failure was the offset, not fp16), sign-alternating
// validation with eps threshold, 128 waves x 8 rows to cut LLC poll
// contention 8x vs round 4 (2KB slot = 32 lines, 2 load-instrs per round,
// half the pollers).
//   p_{t+1} = e_t . (M p_t) / max(p_t),  s2 += log2(max) + 4
//   alpha   = ln2 * (s2 + log2(sum p_T * exp(trans[STOP,:])))

typedef unsigned u32x4 __attribute__((ext_vector_type(4)));

static __device__ __forceinline__ unsigned pk_min(unsigned a, unsigned b) {
    unsigned d; asm("v_pk_min_f16 %0, %1, %2" : "=v"(d) : "v"(a), "v"(b)); return d;
}
static __device__ __forceinline__ unsigned pk_max(unsigned a, unsigned b) {
    unsigned d; asm("v_pk_max_f16 %0, %1, %2" : "=v"(d) : "v"(a), "v"(b)); return d;
}
static __device__ __forceinline__ float fdot2u(unsigned a, unsigned b, float c) {
    asm("v_dot2_f32_f16 %0, %1, %2, %0" : "+v"(c) : "v"(a), "v"(b));
    return c;
}
static __device__ __forceinline__ float hlo(unsigned u) {
    return __half2float(__ushort_as_half((unsigned short)(u & 0xFFFFu)));
}
static __device__ __forceinline__ float hhi(unsigned u) {
    return __half2float(__ushort_as_half((unsigned short)(u >> 16)));
}

template <int CTRL>
static __device__ __forceinline__ float dppf(float x) {
    return __int_as_float(__builtin_amdgcn_update_dpp(
        0, __float_as_int(x), CTRL, 0xF, 0xF, true));
}
// wave64 sum -> lane 63 (round-4-proven: DPP row_shr prefix + shfl folds)
static __device__ __forceinline__ float red_sum64(float x) {
    x += dppf<0x111>(x);
    x += dppf<0x112>(x);
    x += dppf<0x114>(x);
    x += dppf<0x118>(x);
    x += __shfl_xor(x, 16, 64);
    x += __shfl_xor(x, 32, 64);
    return x;
}
static __device__ __forceinline__ float red_max64(float x) {   // x >= 0
    x = fmaxf(x, dppf<0x111>(x));
    x = fmaxf(x, dppf<0x112>(x));
    x = fmaxf(x, dppf<0x114>(x));
    x = fmaxf(x, dppf<0x118>(x));
    x = fmaxf(x, __shfl_xor(x, 16, 64));
    x = fmaxf(x, __shfl_xor(x, 32, 64));
    return x;
}

// 32B agent-coherent load (2x dwordx4, one waitcnt)
static __device__ __forceinline__ void llc_load32B(const void* p,
                                                   u32x4& A, u32x4& B) {
    unsigned long long ap = (unsigned long long)p;
    asm volatile(
        "global_load_dwordx4 %0, %2, off sc1\n\t"
        "global_load_dwordx4 %1, %2, off offset:16 sc1\n\t"
        "s_waitcnt vmcnt(0)"
        : "=&v"(A), "=&v"(B)
        : "v"(ap) : "memory");
}

static __device__ __forceinline__ unsigned long long pk2u(unsigned a, unsigned b) {
    return (unsigned long long)a | ((unsigned long long)b << 32);
}

__global__ __launch_bounds__(TPB)
void crf_forward_kernel(const float* __restrict__ decoded,
                        const float* __restrict__ trans,
                        float* __restrict__ out,
                        unsigned short* __restrict__ ring)
{
    const int lane = threadIdx.x;          // 0..63
    const int wg   = blockIdx.x;           // 0..127
    const int r0   = wg * ROWS;            // this wave's 8 output tags
    const int c0   = 16 * lane;            // this lane's 16 columns

    // M fragments: fp16 pairs, 8 rows x 8 dwords
    unsigned Mh[ROWS][8];
    #pragma unroll
    for (int r = 0; r < ROWS; ++r) {
        #pragma unroll
        for (int k = 0; k < 8; ++k) {
            const float* tp = trans + (size_t)(r0 + r) * NTAGS + c0 + 2 * k;
            unsigned lo = __half_as_ushort(__float2half_rn(__expf(tp[0])));
            unsigned hi = __half_as_ushort(__float2half_rn(__expf(tp[1])));
            Mh[r][k] = lo | (hi << 16);
        }
    }

    double s2 = 0.0;                       // sum (log2 m_t + 4), lane 63
    float4 d0 = make_float4(0,0,0,0), d1 = d0, d0n = d0, d1n = d0;
    if (lane == 63) {
        d0 = *(const float4*)(decoded + r0);
        d1 = *(const float4*)(decoded + r0 + 4);
    }

    for (int t = 0; t < TSTEPS; ++t) {
        // off-critical-path: emissions + next-step prefetch (lane 63 regs)
        float ex[ROWS];
        ex[0]=__expf(d0.x); ex[1]=__expf(d0.y); ex[2]=__expf(d0.z); ex[3]=__expf(d0.w);
        ex[4]=__expf(d1.x); ex[5]=__expf(d1.y); ex[6]=__expf(d1.z); ex[7]=__expf(d1.w);
        if (lane == 63 && t + 1 < TSTEPS) {
            const float* dp = decoded + (size_t)(t + 1) * NTAGS + r0;
            d0n = *(const float4*)dp;
            d1n = *(const float4*)(dp + 4);
        }

        const bool  pos = (((t >> 1) & 1) == 0);
        const float sgf = pos ? 1.0f : -1.0f;

        unsigned q[8];                     // raw stored-form fp16 pairs
        if (t == 0) {
            #pragma unroll
            for (int k = 0; k < 8; ++k) {
                unsigned lo = (c0 + 2*k     == START_I) ? 0x3C00u : 0u;
                unsigned hi = (c0 + 2*k + 1 == START_I) ? 0x3C00u : 0u;
                q[k] = lo | (hi << 16);
            }
        } else {
            const void* src = (const char*)ring + (size_t)(t & 1) * 2048 + 32 * lane;
            u32x4 A, B;
            if (pos) {
                for (;;) {
                    llc_load32B(src, A, B);
                    unsigned mn = pk_min(pk_min(pk_min(A[0],A[1]), pk_min(A[2],A[3])),
                                         pk_min(pk_min(B[0],B[1]), pk_min(B[2],B[3])));
                    if (fminf(hlo(mn), hhi(mn)) >= EPS) break;
                }
            } else {
                for (;;) {
                    llc_load32B(src, A, B);
                    unsigned mx = pk_max(pk_max(pk_max(A[0],A[1]), pk_max(A[2],A[3])),
                                         pk_max(pk_max(B[0],B[1]), pk_max(B[2],B[3])));
                    if (fmaxf(hlo(mx), hhi(mx)) <= -EPS) break;
                }
            }
            q[0]=A[0]; q[1]=A[1]; q[2]=A[2]; q[3]=A[3];
            q[4]=B[0]; q[5]=B[1]; q[6]=B[2]; q[7]=B[3];
        }

        // global max of sg*q  (valid values are all > 0 after sign fix)
        unsigned exq;
        float extf;
        if (pos) {
            exq  = pk_max(pk_max(pk_max(q[0],q[1]), pk_max(q[2],q[3])),
                          pk_max(pk_max(q[4],q[5]), pk_max(q[6],q[7])));
            extf = fmaxf(hlo(exq), hhi(exq));
        } else {
            exq  = pk_min(pk_min(pk_min(q[0],q[1]), pk_min(q[2],q[3])),
                          pk_min(pk_min(q[4],q[5]), pk_min(q[6],q[7])));
            extf = -fminf(hlo(exq), hhi(exq));
        }
        const float m = red_max64(extf);   // lane 63: max of |q| = max(p_scaled)

        // 8-row dot products on raw q; sign fixed once at the end
        float a[ROWS] = {0,0,0,0,0,0,0,0};
        #pragma unroll
        for (int k = 0; k < 8; ++k) {
            #pragma unroll
            for (int r = 0; r < ROWS; ++r)
                a[r] = fdot2u(Mh[r][k], q[k], a[r]);
        }
        #pragma unroll
        for (int r = 0; r < ROWS; ++r) a[r] = red_sum64(a[r]);

        if (lane == 63) {
            const float sc = sgf * SCALE_C * __builtin_amdgcn_rcpf(m);
            s2 += (double)__log2f(m) + LOG2_C;
            unsigned h[ROWS];
            #pragma unroll
            for (int r = 0; r < ROWS; ++r) {
                float o = ex[r] * a[r] * sc;                 // >= 0 up to fp noise
                o = fminf(fmaxf(o, FLOOR_F), CEIL_F);        // also kills NaN/inf
                h[r] = __half_as_ushort(__float2half_rn(o));
            }
            const int      tn   = t + 1;
            const unsigned smsk = (((tn >> 1) & 1)) ? 0x80008000u : 0u;
            unsigned w0 = (h[0] | (h[1] << 16)) ^ smsk;
            unsigned w1 = (h[2] | (h[3] << 16)) ^ smsk;
            unsigned w2 = (h[4] | (h[5] << 16)) ^ smsk;
            unsigned w3 = (h[6] | (h[7] << 16)) ^ smsk;
            unsigned long long* dst =
                (unsigned long long*)((char*)ring + (size_t)(tn & 1) * 2048 + wg * 16);
            __hip_atomic_store(dst,     pk2u(w0, w1),
                               __ATOMIC_RELAXED, __HIP_MEMORY_SCOPE_AGENT);
            __hip_atomic_store(dst + 1, pk2u(w2, w3),
                               __ATOMIC_RELAXED, __HIP_MEMORY_SCOPE_AGENT);
        }
        d0 = d0n; d1 = d1n;
    }

    // ---- epilogue (wg 0): fold in trans[STOP,:] ----
    if (wg == 0) {
        // p_T: slot (16384&1)=0, phase ((16384>>1)&1)=0 -> positive
        const void* src = (const char*)ring + 32 * lane;
        u32x4 A, B;
        for (;;) {
            llc_load32B(src, A, B);
            unsigned mn = pk_min(pk_min(pk_min(A[0],A[1]), pk_min(A[2],A[3])),
                                 pk_min(pk_min(B[0],B[1]), pk_min(B[2],B[3])));
            if (fminf(hlo(mn), hhi(mn)) >= EPS) break;
        }
        unsigned q8[8] = {A[0],A[1],A[2],A[3],B[0],B[1],B[2],B[3]};
        float term = 0.0f;
        #pragma unroll
        for (int k = 0; k < 8; ++k) {
            const float* tp = trans + (size_t)STOP_I * NTAGS + c0 + 2 * k;
            unsigned lo = __half_as_ushort(__float2half_rn(__expf(tp[0])));
            unsigned hi = __half_as_ushort(__float2half_rn(__expf(tp[1])));
            term = fdot2u(lo | (hi << 16), q8[k], term);
        }
        term = red_sum64(term);
        if (lane == 63)
            out[0] = (float)(0.6931471805599453 * (s2 + log2((double)term)));
    }
}

extern "C" void kernel_launch(void* const* d_in, const int* in_sizes, int n_in,
                              void* d_out, int out_size, void* d_ws, size_t ws_size,
                              hipStream_t stream) {
    const float* decoded = (const float*)d_in[0];   // [16384, 1024] f32
    const float* trans   = (const float*)d_in[1];   // [1024, 1024]  f32
    float* out = (float*)d_out;
    unsigned short* ring = (unsigned short*)d_ws;   // 2 slots x 2 KB

    // +/-0 is invalid in BOTH sign phases (threshold EPS > 0).
    hipMemsetAsync(ring, 0x00, 2 * NTAGS * sizeof(unsigned short), stream);

    hipLaunchKernelGGL(crf_forward_kernel, dim3(NWG), dim3(TPB), 0, stream,
                       decoded, trans, out, ring);
}